// Round 5
// baseline (46.653 us; speedup 1.0000x reference)
//
#include <hip/hip_runtime.h>
#include <math.h>
#include <float.h>

#define B_ 2
#define NQ 1024
#define NO 1024
#define LAT 128
#define NHEADS 4
#define RADIUS_ 0.5f
#define LN_EPS_ 1e-5f
#define TILE 512
#define TILE_P (TILE + 8)

#define V_BYTES ((size_t)B_ * NO * LAT * 4)

typedef float v2f __attribute__((ext_vector_type(2)));

// d = s(SGPR pair) * v + c   -- packed fp32, one VOP3P instruction
__device__ __forceinline__ v2f pk_fma_sv(v2f s, v2f v, v2f c) {
  v2f d;
  asm("v_pk_fma_f32 %0, %1, %2, %3" : "=v"(d) : "s"(s), "v"(v), "v"(c));
  return d;
}

__device__ __forceinline__ float selh(int h, float a, float b, float c, float d) {
  return h == 0 ? a : (h == 1 ? b : (h == 2 ? c : d));
}

// workspace: v (B*NO*LAT f32) | A4 (LAT float4) | CWP (64 rows x 16 floats)
// CWP row jp (j=2jp,2jp+1): [C0e,C0o, C1e,C1o, C2e,C2o, w9e,w9o,
//                            w20e,w20o, w21e,w21o, w22e,w22o, w23e,w23o]
// A4[j] = (W1[0]+W1[6], W1[1]+W1[7], W1[2]+W1[8], b1[j])

// ---------------- prep: v = LayerNorm(h_obs) @ Wv + bv, 4 rows/block -------
__global__ __launch_bounds__(256) void gano_prep_kernel(
    const float* __restrict__ h_obs, const float* __restrict__ ln_g,
    const float* __restrict__ ln_b, const float* __restrict__ Wv,
    const float* __restrict__ bv, const float* __restrict__ W1,
    const float* __restrict__ b1, const float* __restrict__ W2,
    float* __restrict__ v_out,
    float4* __restrict__ A4, float* __restrict__ CWP, int write_derived)
{
  const int tid = threadIdx.x;
  const int j = tid & 127;
  const int half = tid >> 7;
  const int wave = tid >> 6;
  const int lane = tid & 63;
  const int r0 = blockIdx.x * 4 + half * 2;

  __shared__ float s_redA[2][4];
  __shared__ float s_redB[2][4];
  __shared__ __align__(16) float s_hn[4][LAT];

  const float x0 = h_obs[(size_t)r0 * LAT + j];
  const float x1 = h_obs[(size_t)(r0 + 1) * LAT + j];
  float s0 = x0, s1 = x1;
  #pragma unroll
  for (int off = 32; off >= 1; off >>= 1) {
    s0 += __shfl_down(s0, off);
    s1 += __shfl_down(s1, off);
  }
  if (lane == 0) { s_redA[0][wave] = s0; s_redA[1][wave] = s1; }
  __syncthreads();
  const float mu0 = (s_redA[0][half * 2] + s_redA[0][half * 2 + 1]) * (1.0f / LAT);
  const float mu1 = (s_redA[1][half * 2] + s_redA[1][half * 2 + 1]) * (1.0f / LAT);
  const float d0 = x0 - mu0, d1 = x1 - mu1;
  float q0 = d0 * d0, q1 = d1 * d1;
  #pragma unroll
  for (int off = 32; off >= 1; off >>= 1) {
    q0 += __shfl_down(q0, off);
    q1 += __shfl_down(q1, off);
  }
  if (lane == 0) { s_redB[0][wave] = q0; s_redB[1][wave] = q1; }
  __syncthreads();
  const float var0 = (s_redB[0][half * 2] + s_redB[0][half * 2 + 1]) * (1.0f / LAT);
  const float var1 = (s_redB[1][half * 2] + s_redB[1][half * 2 + 1]) * (1.0f / LAT);
  const float g = ln_g[j], be = ln_b[j];
  s_hn[half * 2 + 0][j] = d0 * rsqrtf(var0 + LN_EPS_) * g + be;
  s_hn[half * 2 + 1][j] = d1 * rsqrtf(var1 + LN_EPS_) * g + be;
  __syncthreads();

  float a0 = 0.0f, a1 = 0.0f;
  const float4* h0 = (const float4*)s_hn[half * 2 + 0];
  const float4* h1 = (const float4*)s_hn[half * 2 + 1];
  #pragma unroll 4
  for (int k4 = 0; k4 < LAT / 4; ++k4) {
    const float4 u0 = h0[k4];
    const float4 u1 = h1[k4];
    const float w0 = Wv[(k4 * 4 + 0) * LAT + j];
    const float w1 = Wv[(k4 * 4 + 1) * LAT + j];
    const float w2 = Wv[(k4 * 4 + 2) * LAT + j];
    const float w3 = Wv[(k4 * 4 + 3) * LAT + j];
    a0 = fmaf(u0.x, w0, a0); a0 = fmaf(u0.y, w1, a0);
    a0 = fmaf(u0.z, w2, a0); a0 = fmaf(u0.w, w3, a0);
    a1 = fmaf(u1.x, w0, a1); a1 = fmaf(u1.y, w1, a1);
    a1 = fmaf(u1.z, w2, a1); a1 = fmaf(u1.w, w3, a1);
  }
  const float bvj = bv[j];
  v_out[(size_t)(r0 + 0) * LAT + j] = a0 + bvj;
  v_out[(size_t)(r0 + 1) * LAT + j] = a1 + bvj;

  if (write_derived && blockIdx.x == 0) {
    if (tid < LAT) {
      float w[10];
      #pragma unroll
      for (int k = 0; k < 10; ++k) w[k] = W1[k * LAT + tid];
      A4[tid] = make_float4(w[0] + w[6], w[1] + w[7], w[2] + w[8], b1[tid]);
    }
    if (tid < 64) {
      const int je = 2 * tid, jo = 2 * tid + 1;
      float* row = CWP + tid * 16;
      row[0] = W1[3 * LAT + je] - W1[6 * LAT + je];
      row[1] = W1[3 * LAT + jo] - W1[6 * LAT + jo];
      row[2] = W1[4 * LAT + je] - W1[7 * LAT + je];
      row[3] = W1[4 * LAT + jo] - W1[7 * LAT + jo];
      row[4] = W1[5 * LAT + je] - W1[8 * LAT + je];
      row[5] = W1[5 * LAT + jo] - W1[8 * LAT + jo];
      row[6] = W1[9 * LAT + je];
      row[7] = W1[9 * LAT + jo];
      #pragma unroll
      for (int h = 0; h < NHEADS; ++h) {
        row[8 + 2 * h]     = W2[je * NHEADS + h];
        row[8 + 2 * h + 1] = W2[jo * NHEADS + h];
      }
    }
  }
}

// ---------------- MLP logits for one item slot (packed-fp32 j-pairs) -------
template <bool DERIVED>
__device__ __forceinline__ void mlp_logits(
    int t, int Nv, const float* s_Q, const int* s_vidx, const float* s_vdist,
    const float* __restrict__ pob, const float* __restrict__ CWP,
    const float* __restrict__ W1, const float4* __restrict__ W2v,
    float b20, float b21, float b22, float b23,
    float& l0, float& l1, float& l2, float& l3)
{
  const bool active = t < Nv;
  l0 = l1 = l2 = l3 = -FLT_MAX;
  if (!__any(active)) return;
  const int tt = active ? t : Nv - 1;
  const int idx = s_vidx[tt];
  const float dist = s_vdist[tt];
  const float ox = pob[idx * 3 + 0], oy = pob[idx * 3 + 1], oz = pob[idx * 3 + 2];

  if constexpr (DERIVED) {
    const v2f ox2 = {ox, ox}, oy2 = {oy, oy}, oz2 = {oz, oz}, dd2 = {dist, dist};
    v2f A0 = {b20, 0.f}, A1 = {b21, 0.f}, A2 = {b22, 0.f}, A3 = {b23, 0.f};
    #pragma unroll 4
    for (int jp2 = 0; jp2 < 32; ++jp2) {
      const float4 q4 = *(const float4*)&s_Q[jp2 << 2];
      const float* r0 = CWP + ((jp2 * 2 + 0) << 4);
      const float* r1 = CWP + ((jp2 * 2 + 1) << 4);
      {
        v2f gg = {q4.x, q4.y};
        gg = pk_fma_sv(*(const v2f*)(r0 + 0), ox2, gg);
        gg = pk_fma_sv(*(const v2f*)(r0 + 2), oy2, gg);
        gg = pk_fma_sv(*(const v2f*)(r0 + 4), oz2, gg);
        gg = pk_fma_sv(*(const v2f*)(r0 + 6), dd2, gg);
        gg.x = fmaxf(gg.x, 0.0f); gg.y = fmaxf(gg.y, 0.0f);
        A0 = pk_fma_sv(*(const v2f*)(r0 + 8),  gg, A0);
        A1 = pk_fma_sv(*(const v2f*)(r0 + 10), gg, A1);
        A2 = pk_fma_sv(*(const v2f*)(r0 + 12), gg, A2);
        A3 = pk_fma_sv(*(const v2f*)(r0 + 14), gg, A3);
      }
      {
        v2f gg = {q4.z, q4.w};
        gg = pk_fma_sv(*(const v2f*)(r1 + 0), ox2, gg);
        gg = pk_fma_sv(*(const v2f*)(r1 + 2), oy2, gg);
        gg = pk_fma_sv(*(const v2f*)(r1 + 4), oz2, gg);
        gg = pk_fma_sv(*(const v2f*)(r1 + 6), dd2, gg);
        gg.x = fmaxf(gg.x, 0.0f); gg.y = fmaxf(gg.y, 0.0f);
        A0 = pk_fma_sv(*(const v2f*)(r1 + 8),  gg, A0);
        A1 = pk_fma_sv(*(const v2f*)(r1 + 10), gg, A1);
        A2 = pk_fma_sv(*(const v2f*)(r1 + 12), gg, A2);
        A3 = pk_fma_sv(*(const v2f*)(r1 + 14), gg, A3);
      }
    }
    if (active) {
      l0 = A0.x + A0.y; l1 = A1.x + A1.y;
      l2 = A2.x + A2.y; l3 = A3.x + A3.y;
    }
  } else {
    float a0 = b20, a1 = b21, a2 = b22, a3 = b23;
    #pragma unroll 2
    for (int j4 = 0; j4 < LAT / 4; ++j4) {
      const float4 q4 = *(const float4*)&s_Q[j4 << 2];
      #pragma unroll
      for (int u = 0; u < 4; ++u) {
        const int jj = (j4 << 2) + u;
        const float4 cw = make_float4(W1[3 * LAT + jj] - W1[6 * LAT + jj],
                                      W1[4 * LAT + jj] - W1[7 * LAT + jj],
                                      W1[5 * LAT + jj] - W1[8 * LAT + jj],
                                      W1[9 * LAT + jj]);
        const float4 w2 = W2v[jj];
        const float qj = (u == 0) ? q4.x : (u == 1) ? q4.y : (u == 2) ? q4.z : q4.w;
        float gg = fmaf(cw.x, ox, qj);
        gg = fmaf(cw.y, oy, gg);
        gg = fmaf(cw.z, oz, gg);
        gg = fmaf(cw.w, dist, gg);
        gg = fmaxf(gg, 0.0f);
        a0 = fmaf(gg, w2.x, a0);
        a1 = fmaf(gg, w2.y, a1);
        a2 = fmaf(gg, w2.z, a2);
        a3 = fmaf(gg, w2.w, a3);
      }
    }
    if (active) { l0 = a0; l1 = a1; l2 = a2; l3 = a3; }
  }
}

// ---------------- main: one block = one (b,q), 256 threads -----------------
template <bool DERIVED>
__global__ __launch_bounds__(256, 6) void gano_main_kernel(
    const float* __restrict__ pos_obs, const float* __restrict__ pos_query,
    const int* __restrict__ obs_mask,
    const float* __restrict__ W1, const float* __restrict__ b1,
    const float4* __restrict__ W2v, const float* __restrict__ b2,
    const float* __restrict__ v,
    const float4* __restrict__ A4, const float* __restrict__ CWP,
    float* __restrict__ out)
{
  __shared__ __align__(16) float s_Q[LAT];
  __shared__ int   s_vidx[NO];
  __shared__ float s_vdist[NO];
  __shared__ float s_p[NHEADS][TILE_P];
  __shared__ int   s_cnt[16];
  __shared__ float s_red[NHEADS][4];
  __shared__ float s_zred[NHEADS][4];
  __shared__ __align__(16) float s_part[4][LAT];

  const int tid = threadIdx.x;
  const int wave = tid >> 6, lane = tid & 63;
  const int bid = blockIdx.x;
  const int b = bid >> 10, q = bid & (NQ - 1);

  const float qx = pos_query[((size_t)b * NQ + q) * 3 + 0];
  const float qy = pos_query[((size_t)b * NQ + q) * 3 + 1];
  const float qz = pos_query[((size_t)b * NQ + q) * 3 + 2];

  if (tid < LAT) {
    float a0, a1, a2, a3;
    if constexpr (DERIVED) {
      const float4 a = A4[tid];
      a0 = a.x; a1 = a.y; a2 = a.z; a3 = a.w;
    } else {
      a0 = W1[0 * LAT + tid] + W1[6 * LAT + tid];
      a1 = W1[1 * LAT + tid] + W1[7 * LAT + tid];
      a2 = W1[2 * LAT + tid] + W1[8 * LAT + tid];
      a3 = b1[tid];
    }
    s_Q[tid] = fmaf(qx, a0, fmaf(qy, a1, fmaf(qz, a2, a3)));
  }

  // ---- compaction ----
  const float* pob = pos_obs + (size_t)b * NO * 3;
  const int*   om  = obs_mask + (size_t)b * NO;
  float dists[4];
  unsigned long long bals[4];
  #pragma unroll
  for (int rd = 0; rd < 4; ++rd) {
    const int o = (rd << 8) + tid;
    const float ox = pob[o * 3 + 0], oy = pob[o * 3 + 1], oz = pob[o * 3 + 2];
    const float rx = qx - ox, ry = qy - oy, rz = qz - oz;
    const float dist = sqrtf(rx * rx + ry * ry + rz * rz);
    const int ok = (om[o] != 0) && (dist <= RADIUS_);
    const unsigned long long bal = __ballot(ok);
    if (lane == 0) s_cnt[(rd << 2) + wave] = __popcll(bal);
    bals[rd] = bal;
    dists[rd] = dist;
  }
  __syncthreads();
  int Nv = 0;
  #pragma unroll
  for (int k = 0; k < 16; ++k) Nv += s_cnt[k];
  #pragma unroll
  for (int rd = 0; rd < 4; ++rd) {
    const int slot = (rd << 2) + wave;
    int base = 0;
    for (int k = 0; k < slot; ++k) base += s_cnt[k];
    if ((bals[rd] >> lane) & 1ull) {
      const int pos = base + __popcll(bals[rd] & ((1ull << lane) - 1ull));
      s_vidx[pos] = (rd << 8) + tid;
      s_vdist[pos] = dists[rd];
    }
  }
  __syncthreads();

  // ---- per-thread PV mapping ----
  const int c5 = tid & 31;       // column group: cols 4*c5 .. 4*c5+3
  const int phase = tid >> 5;    // item phase 0..7
  const int hh = c5 >> 3;        // head of this column group
  float ax = 0.f, ay = 0.f, az = 0.f, aw = 0.f;
  float m0 = -FLT_MAX, m1 = -FLT_MAX, m2 = -FLT_MAX, m3 = -FLT_MAX;
  float z0 = 0.f, z1 = 0.f, z2 = 0.f, z3 = 0.f;
  const float b20 = b2[0], b21 = b2[1], b22 = b2[2], b23 = b2[3];
  const float* vcol = v + (size_t)b * NO * LAT + (c5 << 2);

  const int ntiles = (Nv + TILE - 1) >> 9;
  for (int tile = 0; tile < ntiles; ++tile) {
    const int tbase = tile << 9;
    float l00, l01, l02, l03, l10, l11, l12, l13;
    mlp_logits<DERIVED>(tbase + tid, Nv, s_Q, s_vidx, s_vdist, pob, CWP, W1, W2v,
                        b20, b21, b22, b23, l00, l01, l02, l03);
    mlp_logits<DERIVED>(tbase + 256 + tid, Nv, s_Q, s_vidx, s_vdist, pob, CWP, W1, W2v,
                        b20, b21, b22, b23, l10, l11, l12, l13);

    // tile max per head
    float t0 = fmaxf(l00, l10), t1 = fmaxf(l01, l11);
    float t2 = fmaxf(l02, l12), t3 = fmaxf(l03, l13);
    #pragma unroll
    for (int off = 32; off >= 1; off >>= 1) {
      t0 = fmaxf(t0, __shfl_down(t0, off));
      t1 = fmaxf(t1, __shfl_down(t1, off));
      t2 = fmaxf(t2, __shfl_down(t2, off));
      t3 = fmaxf(t3, __shfl_down(t3, off));
    }
    if (lane == 0) { s_red[0][wave] = t0; s_red[1][wave] = t1;
                     s_red[2][wave] = t2; s_red[3][wave] = t3; }
    __syncthreads();
    const float x0 = fmaxf(fmaxf(s_red[0][0], s_red[0][1]), fmaxf(s_red[0][2], s_red[0][3]));
    const float x1 = fmaxf(fmaxf(s_red[1][0], s_red[1][1]), fmaxf(s_red[1][2], s_red[1][3]));
    const float x2 = fmaxf(fmaxf(s_red[2][0], s_red[2][1]), fmaxf(s_red[2][2], s_red[2][3]));
    const float x3 = fmaxf(fmaxf(s_red[3][0], s_red[3][1]), fmaxf(s_red[3][2], s_red[3][3]));
    const float nm0 = fmaxf(m0, x0), nm1 = fmaxf(m1, x1);
    const float nm2 = fmaxf(m2, x2), nm3 = fmaxf(m3, x3);
    const float sc0 = __expf(m0 - nm0), sc1 = __expf(m1 - nm1);
    const float sc2 = __expf(m2 - nm2), sc3 = __expf(m3 - nm3);
    m0 = nm0; m1 = nm1; m2 = nm2; m3 = nm3;

    const float p00 = __expf(l00 - nm0), p01 = __expf(l01 - nm1);
    const float p02 = __expf(l02 - nm2), p03 = __expf(l03 - nm3);
    const float p10 = __expf(l10 - nm0), p11 = __expf(l11 - nm1);
    const float p12 = __expf(l12 - nm2), p13 = __expf(l13 - nm3);
    s_p[0][tid] = p00; s_p[0][256 + tid] = p10;
    s_p[1][tid] = p01; s_p[1][256 + tid] = p11;
    s_p[2][tid] = p02; s_p[2][256 + tid] = p12;
    s_p[3][tid] = p03; s_p[3][256 + tid] = p13;
    float u0 = p00 + p10, u1 = p01 + p11, u2 = p02 + p12, u3 = p03 + p13;
    #pragma unroll
    for (int off = 32; off >= 1; off >>= 1) {
      u0 += __shfl_down(u0, off);
      u1 += __shfl_down(u1, off);
      u2 += __shfl_down(u2, off);
      u3 += __shfl_down(u3, off);
    }
    if (lane == 0) { s_zred[0][wave] = u0; s_zred[1][wave] = u1;
                     s_zred[2][wave] = u2; s_zred[3][wave] = u3; }
    __syncthreads();   // also makes s_p visible
    z0 = z0 * sc0 + (s_zred[0][0] + s_zred[0][1] + s_zred[0][2] + s_zred[0][3]);
    z1 = z1 * sc1 + (s_zred[1][0] + s_zred[1][1] + s_zred[1][2] + s_zred[1][3]);
    z2 = z2 * sc2 + (s_zred[2][0] + s_zred[2][1] + s_zred[2][2] + s_zred[2][3]);
    z3 = z3 * sc3 + (s_zred[3][0] + s_zred[3][1] + s_zred[3][2] + s_zred[3][3]);
    const float scme = selh(hh, sc0, sc1, sc2, sc3);
    ax *= scme; ay *= scme; az *= scme; aw *= scme;

    // PV over this tile
    const int tcnt = min(TILE, Nv - tbase);
    int it = phase;
    float bx = 0.f, by = 0.f, bz = 0.f, bw = 0.f;
    for (; it + 8 < tcnt; it += 16) {
      const float pA = s_p[hh][it];
      const float pB = s_p[hh][it + 8];
      const int iA = s_vidx[tbase + it];
      const int iB = s_vidx[tbase + it + 8];
      const float4 vA = *(const float4*)(vcol + (size_t)iA * LAT);
      const float4 vB = *(const float4*)(vcol + (size_t)iB * LAT);
      ax = fmaf(pA, vA.x, ax); ay = fmaf(pA, vA.y, ay);
      az = fmaf(pA, vA.z, az); aw = fmaf(pA, vA.w, aw);
      bx = fmaf(pB, vB.x, bx); by = fmaf(pB, vB.y, by);
      bz = fmaf(pB, vB.z, bz); bw = fmaf(pB, vB.w, bw);
    }
    if (it < tcnt) {
      const float pA = s_p[hh][it];
      const int iA = s_vidx[tbase + it];
      const float4 vA = *(const float4*)(vcol + (size_t)iA * LAT);
      ax = fmaf(pA, vA.x, ax); ay = fmaf(pA, vA.y, ay);
      az = fmaf(pA, vA.z, az); aw = fmaf(pA, vA.w, aw);
    }
    ax += bx; ay += by; az += bz; aw += bw;
    if (tile + 1 < ntiles) __syncthreads();
  }

  // ---- final reduce ----
  ax += __shfl_down(ax, 32);
  ay += __shfl_down(ay, 32);
  az += __shfl_down(az, 32);
  aw += __shfl_down(aw, 32);
  if (lane < 32) {
    *(float4*)&s_part[wave][lane << 2] = make_float4(ax, ay, az, aw);
  }
  __syncthreads();
  if (tid < LAT) {
    const float r4 = s_part[0][tid] + s_part[1][tid] + s_part[2][tid] + s_part[3][tid];
    const int h = tid >> 5;
    const float zz = selh(h, z0, z1, z2, z3);
    const float r = (Nv > 0) ? (r4 / zz) : 0.0f;
    out[((size_t)b * NQ + q) * LAT + tid] = r;
  }
}

extern "C" void kernel_launch(void* const* d_in, const int* in_sizes, int n_in,
                              void* d_out, int out_size, void* d_ws, size_t ws_size,
                              hipStream_t stream) {
  const float* h_obs     = (const float*)d_in[0];
  const float* pos_obs   = (const float*)d_in[1];
  const float* pos_query = (const float*)d_in[2];
  const int*   obs_mask  = (const int*)d_in[3];
  const float* W1        = (const float*)d_in[4];
  const float* b1        = (const float*)d_in[5];
  const float* W2        = (const float*)d_in[6];
  const float* b2        = (const float*)d_in[7];
  const float* ln_g      = (const float*)d_in[8];
  const float* ln_b      = (const float*)d_in[9];
  const float* Wv        = (const float*)d_in[10];
  const float* bv        = (const float*)d_in[11];
  float* outp = (float*)d_out;
  float* v    = (float*)d_ws;

  const size_t need = V_BYTES + LAT * sizeof(float4) + 64 * 16 * sizeof(float);
  const int derived = (ws_size >= need) ? 1 : 0;
  float4* A4  = (float4*)((char*)d_ws + V_BYTES);
  float*  CWP = (float*)(A4 + LAT);
  if (!derived) { A4 = (float4*)d_ws; CWP = (float*)d_ws; }

  gano_prep_kernel<<<(B_ * NO) / 4, 256, 0, stream>>>(h_obs, ln_g, ln_b, Wv, bv,
                                                      W1, b1, W2, v, A4, CWP, derived);
  if (derived) {
    gano_main_kernel<true><<<B_ * NQ, 256, 0, stream>>>(
        pos_obs, pos_query, obs_mask, W1, b1, (const float4*)W2, b2, v,
        (const float4*)A4, CWP, outp);
  } else {
    gano_main_kernel<false><<<B_ * NQ, 256, 0, stream>>>(
        pos_obs, pos_query, obs_mask, W1, b1, (const float4*)W2, b2, v,
        (const float4*)A4, CWP, outp);
  }
}

// Round 6
// 45.963 us; speedup vs baseline: 1.0150x; 1.0150x over previous
//
#include <hip/hip_runtime.h>
#include <math.h>
#include <float.h>

#define B_ 2
#define NQ 1024
#define NO 1024
#define LAT 128
#define NHEADS 4
#define RADIUS_ 0.5f
#define LN_EPS_ 1e-5f
#define PW_STRIDE 68   // floats per (wave,head) p-row; 68*4=272B, 16B-aligned, odd banks

#define V_BYTES ((size_t)B_ * NO * LAT * 4)

__device__ __forceinline__ float selh(int h, float a, float b, float c, float d) {
  return h == 0 ? a : (h == 1 ? b : (h == 2 ? c : d));
}

// ---------------- prep: v = LayerNorm(h_obs) @ Wv + bv, 4 rows/block -------
__global__ __launch_bounds__(256) void gano_prep_kernel(
    const float* __restrict__ h_obs, const float* __restrict__ ln_g,
    const float* __restrict__ ln_b, const float* __restrict__ Wv,
    const float* __restrict__ bv, float* __restrict__ v_out)
{
  const int tid = threadIdx.x;
  const int j = tid & 127;
  const int half = tid >> 7;
  const int wave = tid >> 6;
  const int lane = tid & 63;
  const int r0 = blockIdx.x * 4 + half * 2;

  __shared__ float s_redA[2][4];
  __shared__ float s_redB[2][4];
  __shared__ __align__(16) float s_hn[4][LAT];

  const float x0 = h_obs[(size_t)r0 * LAT + j];
  const float x1 = h_obs[(size_t)(r0 + 1) * LAT + j];
  float s0 = x0, s1 = x1;
  #pragma unroll
  for (int off = 32; off >= 1; off >>= 1) {
    s0 += __shfl_down(s0, off);
    s1 += __shfl_down(s1, off);
  }
  if (lane == 0) { s_redA[0][wave] = s0; s_redA[1][wave] = s1; }
  __syncthreads();
  const float mu0 = (s_redA[0][half * 2] + s_redA[0][half * 2 + 1]) * (1.0f / LAT);
  const float mu1 = (s_redA[1][half * 2] + s_redA[1][half * 2 + 1]) * (1.0f / LAT);
  const float d0 = x0 - mu0, d1 = x1 - mu1;
  float q0 = d0 * d0, q1 = d1 * d1;
  #pragma unroll
  for (int off = 32; off >= 1; off >>= 1) {
    q0 += __shfl_down(q0, off);
    q1 += __shfl_down(q1, off);
  }
  if (lane == 0) { s_redB[0][wave] = q0; s_redB[1][wave] = q1; }
  __syncthreads();
  const float var0 = (s_redB[0][half * 2] + s_redB[0][half * 2 + 1]) * (1.0f / LAT);
  const float var1 = (s_redB[1][half * 2] + s_redB[1][half * 2 + 1]) * (1.0f / LAT);
  const float g = ln_g[j], be = ln_b[j];
  s_hn[half * 2 + 0][j] = d0 * rsqrtf(var0 + LN_EPS_) * g + be;
  s_hn[half * 2 + 1][j] = d1 * rsqrtf(var1 + LN_EPS_) * g + be;
  __syncthreads();

  float a0 = 0.0f, a1 = 0.0f;
  const float4* h0 = (const float4*)s_hn[half * 2 + 0];
  const float4* h1 = (const float4*)s_hn[half * 2 + 1];
  #pragma unroll 4
  for (int k4 = 0; k4 < LAT / 4; ++k4) {
    const float4 u0 = h0[k4];
    const float4 u1 = h1[k4];
    const float w0 = Wv[(k4 * 4 + 0) * LAT + j];
    const float w1 = Wv[(k4 * 4 + 1) * LAT + j];
    const float w2 = Wv[(k4 * 4 + 2) * LAT + j];
    const float w3 = Wv[(k4 * 4 + 3) * LAT + j];
    a0 = fmaf(u0.x, w0, a0); a0 = fmaf(u0.y, w1, a0);
    a0 = fmaf(u0.z, w2, a0); a0 = fmaf(u0.w, w3, a0);
    a1 = fmaf(u1.x, w0, a1); a1 = fmaf(u1.y, w1, a1);
    a1 = fmaf(u1.z, w2, a1); a1 = fmaf(u1.w, w3, a1);
  }
  const float bvj = bv[j];
  v_out[(size_t)(r0 + 0) * LAT + j] = a0 + bvj;
  v_out[(size_t)(r0 + 1) * LAT + j] = a1 + bvj;
}

// ---------------- main: one block = one (b,q); wave-autonomous flash -------
__global__ __launch_bounds__(256, 8) void gano_main_kernel(
    const float* __restrict__ pos_obs, const float* __restrict__ pos_query,
    const int* __restrict__ obs_mask,
    const float* __restrict__ W1, const float* __restrict__ b1,
    const float* __restrict__ W2, const float* __restrict__ b2,
    const float* __restrict__ v, float* __restrict__ out)
{
  __shared__ int   s_vidx[NO];                         // 4 KB
  __shared__ float s_vdist[NO];                        // 4 KB
  __shared__ __align__(16) float s_w[LAT][8];          // 4 KB: C0,C1,C2,w9,W2[0..3]
  __shared__ __align__(16) float s_Q[LAT];             // 512 B
  __shared__ __align__(16) float s_pw[4][NHEADS][PW_STRIDE]; // 4.25 KB, wave-private p
  __shared__ float s_mz[4][2][NHEADS];                 // per-wave m, Z
  __shared__ int   s_cnt[16];

  const int tid = threadIdx.x;
  const int wave = tid >> 6, lane = tid & 63;
  const int bid = blockIdx.x;
  const int b = bid >> 10, q = bid & (NQ - 1);

  const float qx = pos_query[((size_t)b * NQ + q) * 3 + 0];
  const float qy = pos_query[((size_t)b * NQ + q) * 3 + 1];
  const float qz = pos_query[((size_t)b * NQ + q) * 3 + 2];

  // ---- stage derived weights + per-query Q row (coalesced W1 reads) ----
  if (tid < LAT) {
    const int j = tid;
    float w[10];
    #pragma unroll
    for (int k = 0; k < 10; ++k) w[k] = W1[k * LAT + j];
    s_w[j][0] = w[3] - w[6];
    s_w[j][1] = w[4] - w[7];
    s_w[j][2] = w[5] - w[8];
    s_w[j][3] = w[9];
    const float4 w2r = *(const float4*)&W2[j * NHEADS];
    s_w[j][4] = w2r.x; s_w[j][5] = w2r.y; s_w[j][6] = w2r.z; s_w[j][7] = w2r.w;
    s_Q[j] = b1[j] + qx * (w[0] + w[6]) + qy * (w[1] + w[7]) + qz * (w[2] + w[8]);
  }

  // ---- compaction of valid obs (2 barriers) ----
  const float* pob = pos_obs + (size_t)b * NO * 3;
  const int*   om  = obs_mask + (size_t)b * NO;
  float dists[4];
  unsigned long long bals[4];
  #pragma unroll
  for (int rd = 0; rd < 4; ++rd) {
    const int o = (rd << 8) + tid;
    const float ox = pob[o * 3 + 0], oy = pob[o * 3 + 1], oz = pob[o * 3 + 2];
    const float rx = qx - ox, ry = qy - oy, rz = qz - oz;
    const float dist = sqrtf(rx * rx + ry * ry + rz * rz);
    const int ok = (om[o] != 0) && (dist <= RADIUS_);
    const unsigned long long bal = __ballot(ok);
    if (lane == 0) s_cnt[(rd << 2) + wave] = __popcll(bal);
    bals[rd] = bal;
    dists[rd] = dist;
  }
  __syncthreads();
  int Nv = 0;
  #pragma unroll
  for (int k = 0; k < 16; ++k) Nv += s_cnt[k];
  #pragma unroll
  for (int rd = 0; rd < 4; ++rd) {
    const int slot = (rd << 2) + wave;
    int base = 0;
    for (int k = 0; k < slot; ++k) base += s_cnt[k];
    if ((bals[rd] >> lane) & 1ull) {
      const int pos = base + __popcll(bals[rd] & ((1ull << lane) - 1ull));
      s_vidx[pos] = (rd << 8) + tid;
      s_vdist[pos] = dists[rd];
    }
  }
  __syncthreads();   // also publishes s_w / s_Q

  // ---- wave-autonomous flash over this wave's item slice ----
  const int c0 = lane << 1;          // this lane owns cols c0, c0+1
  const int hh = lane >> 4;          // head of those cols
  const float* vbl = v + (size_t)b * NO * LAT + c0;
  const float b20 = b2[0], b21 = b2[1], b22 = b2[2], b23 = b2[3];

  float m0 = -FLT_MAX, m1 = -FLT_MAX, m2 = -FLT_MAX, m3 = -FLT_MAX;
  float z0 = 0.f, z1 = 0.f, z2 = 0.f, z3 = 0.f;
  float ax = 0.f, ay = 0.f;

  for (int cbase = wave << 6; cbase < Nv; cbase += 256) {
    const int cnt = min(64, Nv - cbase);
    const bool act = lane < cnt;
    const int slot = cbase + (act ? lane : (cnt - 1));
    const int idx = s_vidx[slot];
    const float dist = s_vdist[slot];
    const float ox = pob[idx * 3 + 0], oy = pob[idx * 3 + 1], oz = pob[idx * 3 + 2];

    // MLP: 128-j loop, weights broadcast from LDS
    float a0 = b20, a1 = b21, a2 = b22, a3 = b23;
    #pragma unroll 2
    for (int j4 = 0; j4 < LAT / 4; ++j4) {
      const float4 q4 = *(const float4*)&s_Q[j4 << 2];
      #pragma unroll
      for (int u = 0; u < 4; ++u) {
        const int j = (j4 << 2) + u;
        const float4 cw = *(const float4*)&s_w[j][0];
        const float4 w2 = *(const float4*)&s_w[j][4];
        const float qj = (u == 0) ? q4.x : (u == 1) ? q4.y : (u == 2) ? q4.z : q4.w;
        float gg = fmaf(cw.x, ox, qj);
        gg = fmaf(cw.y, oy, gg);
        gg = fmaf(cw.z, oz, gg);
        gg = fmaf(cw.w, dist, gg);
        gg = fmaxf(gg, 0.0f);
        a0 = fmaf(gg, w2.x, a0);
        a1 = fmaf(gg, w2.y, a1);
        a2 = fmaf(gg, w2.z, a2);
        a3 = fmaf(gg, w2.w, a3);
      }
    }
    const float l0 = act ? a0 : -FLT_MAX;
    const float l1 = act ? a1 : -FLT_MAX;
    const float l2 = act ? a2 : -FLT_MAX;
    const float l3 = act ? a3 : -FLT_MAX;

    // wave-private per-head chunk max (shfl-only, no barriers)
    float x0 = l0, x1 = l1, x2 = l2, x3 = l3;
    #pragma unroll
    for (int off = 1; off < 64; off <<= 1) {
      x0 = fmaxf(x0, __shfl_xor(x0, off));
      x1 = fmaxf(x1, __shfl_xor(x1, off));
      x2 = fmaxf(x2, __shfl_xor(x2, off));
      x3 = fmaxf(x3, __shfl_xor(x3, off));
    }
    const float nm0 = fmaxf(m0, x0), nm1 = fmaxf(m1, x1);
    const float nm2 = fmaxf(m2, x2), nm3 = fmaxf(m3, x3);
    const float sc0 = __expf(m0 - nm0), sc1 = __expf(m1 - nm1);
    const float sc2 = __expf(m2 - nm2), sc3 = __expf(m3 - nm3);
    m0 = nm0; m1 = nm1; m2 = nm2; m3 = nm3;

    const float p0 = __expf(l0 - nm0);
    const float p1 = __expf(l1 - nm1);
    const float p2 = __expf(l2 - nm2);
    const float p3 = __expf(l3 - nm3);
    s_pw[wave][0][lane] = p0;
    s_pw[wave][1][lane] = p1;
    s_pw[wave][2][lane] = p2;
    s_pw[wave][3][lane] = p3;
    z0 = z0 * sc0 + p0;
    z1 = z1 * sc1 + p1;
    z2 = z2 * sc2 + p2;
    z3 = z3 * sc3 + p3;
    const float sch = selh(hh, sc0, sc1, sc2, sc3);
    ax *= sch; ay *= sch;

    // PV over this chunk (wave-private; compiler inserts lgkmcnt wait)
    const float* pr = s_pw[wave][hh];
    for (int it = 0; it < cnt; it += 4) {
      const float4 pq = *(const float4*)&pr[it];
      const int4 iq = *(const int4*)&s_vidx[cbase + it];
      const int i0 = iq.x & (NO - 1), i1 = iq.y & (NO - 1);
      const int i2 = iq.z & (NO - 1), i3 = iq.w & (NO - 1);
      const float2 v0 = *(const float2*)(vbl + (size_t)i0 * LAT);
      const float2 v1 = *(const float2*)(vbl + (size_t)i1 * LAT);
      const float2 v2 = *(const float2*)(vbl + (size_t)i2 * LAT);
      const float2 v3 = *(const float2*)(vbl + (size_t)i3 * LAT);
      ax = fmaf(pq.x, v0.x, ax); ay = fmaf(pq.x, v0.y, ay);
      ax = fmaf(pq.y, v1.x, ax); ay = fmaf(pq.y, v1.y, ay);
      ax = fmaf(pq.z, v2.x, ax); ay = fmaf(pq.z, v2.y, ay);
      ax = fmaf(pq.w, v3.x, ax); ay = fmaf(pq.w, v3.y, ay);
    }
  }

  // ---- per-wave epilogue: reduce Z, publish m/Z/partial ----
  #pragma unroll
  for (int off = 1; off < 64; off <<= 1) {
    z0 += __shfl_xor(z0, off);
    z1 += __shfl_xor(z1, off);
    z2 += __shfl_xor(z2, off);
    z3 += __shfl_xor(z3, off);
  }
  if (lane == 0) {
    s_mz[wave][0][0] = m0; s_mz[wave][0][1] = m1;
    s_mz[wave][0][2] = m2; s_mz[wave][0][3] = m3;
    s_mz[wave][1][0] = z0; s_mz[wave][1][1] = z1;
    s_mz[wave][1][2] = z2; s_mz[wave][1][3] = z3;
  }
  // reuse this wave's (now dead) p-buffer for the PV partial
  float* part = &s_pw[wave][0][0];
  part[c0] = ax; part[c0 + 1] = ay;
  __syncthreads();

  // ---- combine 4 wave-partials ----
  if (tid < LAT) {
    const int h = tid >> 5;
    const float mw0 = s_mz[0][0][h], mw1 = s_mz[1][0][h];
    const float mw2 = s_mz[2][0][h], mw3 = s_mz[3][0][h];
    const float M = fmaxf(fmaxf(mw0, mw1), fmaxf(mw2, mw3));
    float num = 0.f, den = 0.f;
    #pragma unroll
    for (int w = 0; w < 4; ++w) {
      const float e = __expf(s_mz[w][0][h] - M);
      num = fmaf(e, (&s_pw[w][0][0])[tid], num);
      den = fmaf(e, s_mz[w][1][h], den);
    }
    const float r = (Nv > 0) ? (num / den) : 0.0f;
    out[((size_t)b * NQ + q) * LAT + tid] = r;
  }
}

extern "C" void kernel_launch(void* const* d_in, const int* in_sizes, int n_in,
                              void* d_out, int out_size, void* d_ws, size_t ws_size,
                              hipStream_t stream) {
  const float* h_obs     = (const float*)d_in[0];
  const float* pos_obs   = (const float*)d_in[1];
  const float* pos_query = (const float*)d_in[2];
  const int*   obs_mask  = (const int*)d_in[3];
  const float* W1        = (const float*)d_in[4];
  const float* b1        = (const float*)d_in[5];
  const float* W2        = (const float*)d_in[6];
  const float* b2        = (const float*)d_in[7];
  const float* ln_g      = (const float*)d_in[8];
  const float* ln_b      = (const float*)d_in[9];
  const float* Wv        = (const float*)d_in[10];
  const float* bv        = (const float*)d_in[11];
  float* outp = (float*)d_out;
  float* v    = (float*)d_ws;   // 1 MB

  gano_prep_kernel<<<(B_ * NO) / 4, 256, 0, stream>>>(h_obs, ln_g, ln_b, Wv, bv, v);
  gano_main_kernel<<<B_ * NQ, 256, 0, stream>>>(pos_obs, pos_query, obs_mask,
                                                W1, b1, W2, b2, v, outp);
}